// Round 2
// baseline (963.137 us; speedup 1.0000x reference)
//
#include <hip/hip_runtime.h>
#include <math.h>

// AttentionAggregator2 fused kernels for MI355X (gfx950).
// v3: single fused kernel (pre merged into attn). Harness re-poison fills
// (~500 us of 1.6 GB fillBuffer) dominate the timed region; our controllable
// portion is setup + one streaming kernel at the HBM roofline (~694 MB).
// Per block (8 nodes, 8 waves): every wave redundantly computes t1 =
// tanh(x@W1a) for the block's 8 nodes (8 MFMA, L1-hot x), keeps only its own
// node's row (per-wave LDS strip, same-wave RAW -> no barrier), builds u in
// registers, reuses the x A-frags for the x@Wfx epilogue, then scores +
// in-register masked softmax + L2-served aggregation. One barrier total
// (aggL exchange for agg@Wfn).
// Key algebra: ws[n,k] = tanh(ne@W2a) . u[n], u[n] = M^T tanh(x@W1a),
// M = W1b @ W2b^T.

typedef _Float16 half_t;
typedef __attribute__((ext_vector_type(4))) _Float16 half4_t;
typedef __attribute__((ext_vector_type(8))) _Float16 half8_t;
typedef __attribute__((ext_vector_type(4))) float f32x4;

#define NN   50000
#define GK   16     // neighbors per node
#define DIN  128
#define DED  64
#define DNE  192    // DIN + DED

// workspace byte offsets (written fresh by setup_kernel every launch)
#define WS_M    0        // 32x32 f32: M = W1b @ W2b^T
#define WS_W1A  4096     // 2 tiles * 4 ksteps * 64 lanes * 8 halfs
#define WS_W2A  12288    // 2 * 6 * 512
#define WS_WFX  24576    // 8 * 4 * 512
#define WS_WFN  57344    // 8 * 6 * 512   (total 106496 B of d_ws used)

// Pre-swizzle weight matrix W[K x ncol] into MFMA B-fragment order:
// frag element ((t*S+s)*64 + lane)*8 + j  <=  W[32s + (lane>>4)*8 + j][16t + (lane&15)]
__device__ __forceinline__ void swz(const float* __restrict__ W, int ncol, int S,
                                    half_t* __restrict__ dst, int tid, int nth) {
  int T = ncol >> 4;
  int total = T * S * 512;
  for (int i = tid; i < total; i += nth) {
    int j = i & 7;
    int l = (i >> 3) & 63;
    int rest = i >> 9;
    int s = rest % S;
    int t = rest / S;
    int k = 32 * s + (l >> 4) * 8 + j;
    int n = 16 * t + (l & 15);
    dst[i] = (half_t)W[k * ncol + n];
  }
}

__global__ void setup_kernel(const float* __restrict__ W1a, const float* __restrict__ W1b,
                             const float* __restrict__ W2a, const float* __restrict__ W2b,
                             const float* __restrict__ Wfx, const float* __restrict__ Wfn,
                             unsigned char* __restrict__ ws) {
  int tid = blockIdx.x * blockDim.x + threadIdx.x;
  int nth = gridDim.x * blockDim.x;
  float* Mm = (float*)(ws + WS_M);
  for (int i = tid; i < 1024; i += nth) {        // M[a][h] = sum_h2 W1b[a][h2]*W2b[h][h2]
    int a = i >> 5, h = i & 31;
    float acc = 0.f;
    for (int h2 = 0; h2 < 32; ++h2)
      acc = fmaf(W1b[a * 32 + h2], W2b[h * 32 + h2], acc);
    Mm[i] = acc;
  }
  swz(W1a, 32, 4, (half_t*)(ws + WS_W1A), tid, nth);
  swz(W2a, 32, 6, (half_t*)(ws + WS_W2A), tid, nth);
  swz(Wfx, 128, 4, (half_t*)(ws + WS_WFX), tid, nth);
  swz(Wfn, 128, 6, (half_t*)(ws + WS_WFN), tid, nth);
}

__device__ __forceinline__ half8_t cvt8(float4 a, float4 b) {
  half8_t r;
  r[0] = (half_t)a.x; r[1] = (half_t)a.y; r[2] = (half_t)a.z; r[3] = (half_t)a.w;
  r[4] = (half_t)b.x; r[5] = (half_t)b.y; r[6] = (half_t)b.z; r[7] = (half_t)b.w;
  return r;
}

__device__ __forceinline__ float elu(float v) { return v > 0.f ? v : expm1f(v); }

// ---------------------------------------------------------------------------
// attn_kernel: one wave per node (8 waves/block). Single barrier per block.
// ---------------------------------------------------------------------------
__global__ __launch_bounds__(512, 4)
void attn_kernel(const float* __restrict__ x, const float* __restrict__ neibs,
                 const float* __restrict__ edge, const float* __restrict__ mask,
                 const unsigned char* __restrict__ ws, float* __restrict__ out) {
  __shared__ __align__(16) half_t aggL[16][200];   // 6400 B; rows 8..15 stay 0
  __shared__ float t1L[8][33];                     // per-wave t1 row (own node)
  const int tid = threadIdx.x;
  const int wave = tid >> 6, lane = tid & 63;
  const int l15 = lane & 15, q = lane >> 4;
  const int n = blockIdx.x * 8 + wave;             // 6250 * 8 = 50000 exact
  const float* Mm = (const float*)(ws + WS_M);
  const half_t* w1a = (const half_t*)(ws + WS_W1A);
  const half_t* w2a = (const half_t*)(ws + WS_W2A);
  const half_t* wfx = (const half_t*)(ws + WS_WFX);
  const half_t* wfn = (const half_t*)(ws + WS_WFN);

  // zero agg rows 8..15 only (disjoint from rows 0..7 -> no race)
  for (int i = tid; i < 800; i += 512)
    ((unsigned int*)&aggL[8][0])[i] = 0u;

  // ---- x A-fragments for the block's 8 nodes (rows dup'd into 8..15) ----
  const float* xrow = x + (size_t)(blockIdx.x * 8 + (l15 & 7)) * DIN;
  half8_t Ax[4];
#pragma unroll
  for (int s = 0; s < 4; ++s) {
    float4 a0 = *(const float4*)(xrow + 32 * s + 8 * q);
    float4 a1 = *(const float4*)(xrow + 32 * s + 8 * q + 4);
    Ax[s] = cvt8(a0, a1);
  }

  // ---- t1 = tanh(x @ W1a), redundantly per wave; keep only row `wave` ----
  {
    f32x4 t0 = {0.f, 0.f, 0.f, 0.f}, t1 = {0.f, 0.f, 0.f, 0.f};
#pragma unroll
    for (int s = 0; s < 4; ++s) {
      half8_t B0 = *(const half8_t*)(w1a + ((size_t)(0 * 4 + s) * 64 + lane) * 8);
      half8_t B1 = *(const half8_t*)(w1a + ((size_t)(1 * 4 + s) * 64 + lane) * 8);
      t0 = __builtin_amdgcn_mfma_f32_16x16x32_f16(Ax[s], B0, t0, 0, 0, 0);
      t1 = __builtin_amdgcn_mfma_f32_16x16x32_f16(Ax[s], B1, t1, 0, 0, 0);
    }
#pragma unroll
    for (int r = 0; r < 4; ++r) {                  // C row = 4q+r; keep row==wave
      if (4 * q + r == wave) {
        t1L[wave][l15]      = tanhf(t0[r]);
        t1L[wave][16 + l15] = tanhf(t1[r]);
      }
    }
  }

  // ---- u[h] = sum_a t1[a]*M[a][h]; lane holds h=l15 (u0) and 16+l15 (u1) ----
  // same-wave LDS RAW (broadcast reads), no barrier needed
  float u0 = 0.f, u1 = 0.f;
#pragma unroll
  for (int a = 0; a < 32; ++a) {
    float tv = t1L[wave][a];
    u0 = fmaf(tv, Mm[a * 32 + l15], u0);
    u1 = fmaf(tv, Mm[a * 32 + 16 + l15], u1);
  }

  // ---- x @ Wfx epilogue (col tile = wave), frees Ax ----
  {
    f32x4 accx = {0.f, 0.f, 0.f, 0.f};
#pragma unroll
    for (int s = 0; s < 4; ++s) {
      half8_t B = *(const half8_t*)(wfx + ((size_t)(wave * 4 + s) * 64 + lane) * 8);
      accx = __builtin_amdgcn_mfma_f32_16x16x32_f16(Ax[s], B, accx, 0, 0, 0);
    }
    const size_t ob = (size_t)blockIdx.x * 8 * 256;
#pragma unroll
    for (int r = 0; r < 4; ++r) {
      int m = 4 * q + r;                           // rows 8..15 are dup garbage
      if (m < 8)
        out[ob + (size_t)m * 256 + wave * 16 + l15] = elu(accx[r]);
    }
  }

  // ---- scores: S = tanh(ne @ W2a) [16 x 32]; A rows = neighbors k = l15 ----
  f32x4 acc0 = {0.f, 0.f, 0.f, 0.f}, acc1 = {0.f, 0.f, 0.f, 0.f};
  const float* nbase = neibs + (size_t)n * (GK * DIN);
  const float* ebase = edge + (size_t)n * (GK * DED);
  const float* nrow = nbase + l15 * DIN;
  const float* erow = ebase + l15 * DED;
#pragma unroll
  for (int s = 0; s < 4; ++s) {
    float4 a0 = *(const float4*)(nrow + 32 * s + 8 * q);
    float4 a1 = *(const float4*)(nrow + 32 * s + 8 * q + 4);
    half8_t A = cvt8(a0, a1);
    half8_t B0 = *(const half8_t*)(w2a + ((size_t)(0 * 6 + s) * 64 + lane) * 8);
    half8_t B1 = *(const half8_t*)(w2a + ((size_t)(1 * 6 + s) * 64 + lane) * 8);
    acc0 = __builtin_amdgcn_mfma_f32_16x16x32_f16(A, B0, acc0, 0, 0, 0);
    acc1 = __builtin_amdgcn_mfma_f32_16x16x32_f16(A, B1, acc1, 0, 0, 0);
  }
#pragma unroll
  for (int s = 0; s < 2; ++s) {
    float4 a0 = *(const float4*)(erow + 32 * s + 8 * q);
    float4 a1 = *(const float4*)(erow + 32 * s + 8 * q + 4);
    half8_t A = cvt8(a0, a1);
    half8_t B0 = *(const half8_t*)(w2a + ((size_t)(0 * 6 + 4 + s) * 64 + lane) * 8);
    half8_t B1 = *(const half8_t*)(w2a + ((size_t)(1 * 6 + 4 + s) * 64 + lane) * 8);
    acc0 = __builtin_amdgcn_mfma_f32_16x16x32_f16(A, B0, acc0, 0, 0, 0);
    acc1 = __builtin_amdgcn_mfma_f32_16x16x32_f16(A, B1, acc1, 0, 0, 0);
  }

  // s[k] = sum_h tanh(S[k][h]) * u[h]; lane holds col h=l15(+16), rows k=4q+r
  float sv[4];
#pragma unroll
  for (int r = 0; r < 4; ++r)
    sv[r] = tanhf(acc0[r]) * u0 + tanhf(acc1[r]) * u1;
#pragma unroll
  for (int off = 1; off <= 8; off <<= 1)
#pragma unroll
    for (int r = 0; r < 4; ++r)
      sv[r] += __shfl_xor(sv[r], off);   // reduce over 16 cols; k=4q+r replicated

  // ---- masked softmax fully in registers (all 64 lanes participate) ----
  float e[4];
  float mx = -3.4e38f;
#pragma unroll
  for (int r = 0; r < 4; ++r) {
    sv[r] -= 9999999.0f * mask[(size_t)n * GK + 4 * q + r];
    mx = fmaxf(mx, sv[r]);
  }
  mx = fmaxf(mx, __shfl_xor(mx, 16));
  mx = fmaxf(mx, __shfl_xor(mx, 32));
  float sm = 0.f;
#pragma unroll
  for (int r = 0; r < 4; ++r) { e[r] = expf(sv[r] - mx); sm += e[r]; }
  sm += __shfl_xor(sm, 16);
  sm += __shfl_xor(sm, 32);
  const float rs = 1.0f / sm;
#pragma unroll
  for (int r = 0; r < 4; ++r) e[r] *= rs;   // weight for k=4q+r

  // ---- aggregation: lane owns d = lane, 64+lane, edge lane; ne from L2 ----
  float a0 = 0.f, a1 = 0.f, a2 = 0.f;
#pragma unroll
  for (int k = 0; k < GK; ++k) {
    float wv = __shfl(e[k & 3], (k & 12) << 2);   // lane 16*(k>>2) holds k's weight
    a0 = fmaf(wv, nbase[k * DIN + lane], a0);
    a1 = fmaf(wv, nbase[k * DIN + 64 + lane], a1);
    a2 = fmaf(wv, ebase[k * DED + lane], a2);
  }
  aggL[wave][lane] = (half_t)a0;
  aggL[wave][64 + lane] = (half_t)a1;
  aggL[wave][128 + lane] = (half_t)a2;
  __syncthreads();

  // ---- epilogue: out[:,128:] = elu(agg @ Wfn); wave = col tile ----
  f32x4 accn = {0.f, 0.f, 0.f, 0.f};
#pragma unroll
  for (int s = 0; s < 6; ++s) {
    half8_t A = *(const half8_t*)(&aggL[l15][32 * s + 8 * q]);
    half8_t B = *(const half8_t*)(wfn + ((size_t)(wave * 6 + s) * 64 + lane) * 8);
    accn = __builtin_amdgcn_mfma_f32_16x16x32_f16(A, B, accn, 0, 0, 0);
  }
  const size_t ob = (size_t)blockIdx.x * 8 * 256;
#pragma unroll
  for (int r = 0; r < 4; ++r) {
    int m = 4 * q + r;                   // C row = node (rows 8..15 are zeros)
    if (m < 8)
      out[ob + (size_t)m * 256 + 128 + wave * 16 + l15] = elu(accn[r]);
  }
}

extern "C" void kernel_launch(void* const* d_in, const int* in_sizes, int n_in,
                              void* d_out, int out_size, void* d_ws, size_t ws_size,
                              hipStream_t stream) {
  const float* x     = (const float*)d_in[0];
  const float* neibs = (const float*)d_in[1];
  const float* edge  = (const float*)d_in[2];
  const float* mask  = (const float*)d_in[3];
  const float* W1a   = (const float*)d_in[4];
  const float* W1b   = (const float*)d_in[5];
  const float* W2a   = (const float*)d_in[6];
  const float* W2b   = (const float*)d_in[7];
  const float* Wfx   = (const float*)d_in[8];
  const float* Wfn   = (const float*)d_in[9];
  float* out = (float*)d_out;
  unsigned char* ws = (unsigned char*)d_ws;

  hipLaunchKernelGGL(setup_kernel, dim3(64), dim3(256), 0, stream,
                     W1a, W1b, W2a, W2b, Wfx, Wfn, ws);
  hipLaunchKernelGGL(attn_kernel, dim3(NN / 8), dim3(512), 0, stream,
                     x, neibs, edge, mask, ws, out);
}

// Round 3
// 756.374 us; speedup vs baseline: 1.2734x; 1.2734x over previous
//
#include <hip/hip_runtime.h>
#include <math.h>

// AttentionAggregator2 fused kernels for MI355X (gfx950).
// v4: revert to the proven v1 two-kernel split (v3's merge caused 6x write
// amplification (WRITE_SIZE 325MB) + VGPR-64 serialization of the per-wave
// chain). attn now processes 2 nodes per wave: doubles independent
// load/MFMA streams per wave (latency hiding at the observed ~2 WG/CU cap),
// shares W2a B-frags across nodes, fills all 16 epilogue MFMA rows with real
// nodes, and keeps all out writes wave-synchronous post-barrier (full lines).
//   pre_kernel : t1=tanh(x@W1a), u=t1@M -> parked in out[:,128:160];
//                out[:,0:128] = elu(x@Wfx).
//   attn_kernel: scores + in-register masked softmax + L2-served aggregation
//                + agg@Wfn epilogue. One barrier.
// Key algebra: ws[n,k] = tanh(ne@W2a) . u[n], u[n] = M^T tanh(x@W1a),
// M = W1b @ W2b^T.

typedef _Float16 half_t;
typedef __attribute__((ext_vector_type(4))) _Float16 half4_t;
typedef __attribute__((ext_vector_type(8))) _Float16 half8_t;
typedef __attribute__((ext_vector_type(4))) float f32x4;

#define NN   50000
#define GK   16     // neighbors per node
#define DIN  128
#define DED  64
#define DNE  192    // DIN + DED

// workspace byte offsets (written fresh by setup_kernel every launch)
#define WS_M    0        // 32x32 f32: M = W1b @ W2b^T
#define WS_W1A  4096     // 2 tiles * 4 ksteps * 64 lanes * 8 halfs
#define WS_W2A  12288    // 2 * 6 * 512
#define WS_WFX  24576    // 8 * 4 * 512
#define WS_WFN  57344    // 8 * 6 * 512   (total 106496 B of d_ws used)

// Pre-swizzle weight matrix W[K x ncol] into MFMA B-fragment order:
// frag element ((t*S+s)*64 + lane)*8 + j  <=  W[32s + (lane>>4)*8 + j][16t + (lane&15)]
__device__ __forceinline__ void swz(const float* __restrict__ W, int ncol, int S,
                                    half_t* __restrict__ dst, int tid, int nth) {
  int T = ncol >> 4;
  int total = T * S * 512;
  for (int i = tid; i < total; i += nth) {
    int j = i & 7;
    int l = (i >> 3) & 63;
    int rest = i >> 9;
    int s = rest % S;
    int t = rest / S;
    int k = 32 * s + (l >> 4) * 8 + j;
    int n = 16 * t + (l & 15);
    dst[i] = (half_t)W[k * ncol + n];
  }
}

__global__ void setup_kernel(const float* __restrict__ W1a, const float* __restrict__ W1b,
                             const float* __restrict__ W2a, const float* __restrict__ W2b,
                             const float* __restrict__ Wfx, const float* __restrict__ Wfn,
                             unsigned char* __restrict__ ws) {
  int tid = blockIdx.x * blockDim.x + threadIdx.x;
  int nth = gridDim.x * blockDim.x;
  float* Mm = (float*)(ws + WS_M);
  for (int i = tid; i < 1024; i += nth) {        // M[a][h] = sum_h2 W1b[a][h2]*W2b[h][h2]
    int a = i >> 5, h = i & 31;
    float acc = 0.f;
    for (int h2 = 0; h2 < 32; ++h2)
      acc = fmaf(W1b[a * 32 + h2], W2b[h * 32 + h2], acc);
    Mm[i] = acc;
  }
  swz(W1a, 32, 4, (half_t*)(ws + WS_W1A), tid, nth);
  swz(W2a, 32, 6, (half_t*)(ws + WS_W2A), tid, nth);
  swz(Wfx, 128, 4, (half_t*)(ws + WS_WFX), tid, nth);
  swz(Wfn, 128, 6, (half_t*)(ws + WS_WFN), tid, nth);
}

__device__ __forceinline__ half8_t cvt8(float4 a, float4 b) {
  half8_t r;
  r[0] = (half_t)a.x; r[1] = (half_t)a.y; r[2] = (half_t)a.z; r[3] = (half_t)a.w;
  r[4] = (half_t)b.x; r[5] = (half_t)b.y; r[6] = (half_t)b.z; r[7] = (half_t)b.w;
  return r;
}

__device__ __forceinline__ float elu(float v) { return v > 0.f ? v : expm1f(v); }

// ---------------------------------------------------------------------------
// pre_kernel: per wave, 16 nodes. Computes t1 = tanh(x@W1a), u = t1@M,
// outx = elu(x@Wfx). Writes out[n][0:128] = outx, out[n][128:160] = u (f32,
// temporary storage; attn_kernel reads it pre-barrier and overwrites later).
// ---------------------------------------------------------------------------
__global__ __launch_bounds__(256, 4)
void pre_kernel(const float* __restrict__ x, const unsigned char* __restrict__ ws,
                float* __restrict__ out) {
  __shared__ float t1L[64][33];
  const int tid = threadIdx.x;
  const int wave = tid >> 6, lane = tid & 63;
  const int l15 = lane & 15, q = lane >> 4;
  const int nb0 = blockIdx.x * 64;
  const int n0 = nb0 + wave * 16;
  const float* Mm = (const float*)(ws + WS_M);
  const half_t* w1a = (const half_t*)(ws + WS_W1A);
  const half_t* wfx = (const half_t*)(ws + WS_WFX);

  int row = n0 + l15; if (row >= NN) row = NN - 1;   // clamped tail
  const float* xrow = x + (size_t)row * DIN;
  half8_t Ax[4];
  f32x4 t0acc = {0.f, 0.f, 0.f, 0.f}, t1acc = {0.f, 0.f, 0.f, 0.f};
#pragma unroll
  for (int s = 0; s < 4; ++s) {
    float4 a0 = *(const float4*)(xrow + 32 * s + 8 * q);
    float4 a1 = *(const float4*)(xrow + 32 * s + 8 * q + 4);
    Ax[s] = cvt8(a0, a1);
    half8_t B0 = *(const half8_t*)(w1a + ((size_t)(0 * 4 + s) * 64 + lane) * 8);
    half8_t B1 = *(const half8_t*)(w1a + ((size_t)(1 * 4 + s) * 64 + lane) * 8);
    t0acc = __builtin_amdgcn_mfma_f32_16x16x32_f16(Ax[s], B0, t0acc, 0, 0, 0);
    t1acc = __builtin_amdgcn_mfma_f32_16x16x32_f16(Ax[s], B1, t1acc, 0, 0, 0);
  }
#pragma unroll
  for (int r = 0; r < 4; ++r) {                      // C: col=l15, row=4q+r
    t1L[wave * 16 + 4 * q + r][l15]      = tanhf(t0acc[r]);
    t1L[wave * 16 + 4 * q + r][16 + l15] = tanhf(t1acc[r]);
  }
  __syncthreads();

  // u[g][h] = sum_a t1[g][a] * M[a][h]; 64 nodes x 32 h / 256 threads
#pragma unroll
  for (int i = 0; i < 8; ++i) {
    int idx = i * 256 + tid;
    int g = idx >> 5, h = idx & 31;
    float acc = 0.f;
#pragma unroll
    for (int a = 0; a < 32; ++a)
      acc = fmaf(t1L[g][a], Mm[a * 32 + h], acc);
    int n = nb0 + g;
    if (n < NN) out[(size_t)n * 256 + 128 + h] = acc;   // u parked in out
  }

  // outx = elu(x @ Wfx), col tile t
#pragma unroll
  for (int t = 0; t < 8; ++t) {
    f32x4 acc = {0.f, 0.f, 0.f, 0.f};
#pragma unroll
    for (int s = 0; s < 4; ++s) {
      half8_t B = *(const half8_t*)(wfx + ((size_t)(t * 4 + s) * 64 + lane) * 8);
      acc = __builtin_amdgcn_mfma_f32_16x16x32_f16(Ax[s], B, acc, 0, 0, 0);
    }
#pragma unroll
    for (int r = 0; r < 4; ++r) {
      int m = n0 + 4 * q + r;
      if (m < NN) out[(size_t)m * 256 + t * 16 + l15] = elu(acc[r]);
    }
  }
}

// ---------------------------------------------------------------------------
// attn_kernel: 2 nodes per wave, 8 waves -> 16 nodes/block (3125 blocks).
// Doubled ILP per wave; shared W2a B-frags; all-16-row epilogue MFMA;
// single barrier; wave-synchronous full-line out writes.
// ---------------------------------------------------------------------------
__global__ __launch_bounds__(512, 4)
void attn_kernel(const float* __restrict__ neibs, const float* __restrict__ edge,
                 const float* __restrict__ mask, const unsigned char* __restrict__ ws,
                 float* __restrict__ out) {
  __shared__ __align__(16) half_t aggL[16][200];   // 6400 B; all 16 rows real
  const int tid = threadIdx.x;
  const int wave = tid >> 6, lane = tid & 63;
  const int l15 = lane & 15, q = lane >> 4;
  const int nb = blockIdx.x * 16;                  // 3125 * 16 = 50000 exact
  const int n0 = nb + wave * 2;                    // this wave's two nodes
  const half_t* w2a = (const half_t*)(ws + WS_W2A);
  const half_t* wfn = (const half_t*)(ws + WS_WFN);

  const float* nbase0 = neibs + (size_t)n0 * (GK * DIN);
  const float* nbase1 = nbase0 + GK * DIN;
  const float* ebase0 = edge + (size_t)n0 * (GK * DED);
  const float* ebase1 = ebase0 + GK * DED;
  const float* nrow0 = nbase0 + l15 * DIN;
  const float* nrow1 = nbase1 + l15 * DIN;
  const float* erow0 = ebase0 + l15 * DED;
  const float* erow1 = ebase1 + l15 * DED;

  // ---- scores: S = tanh(ne @ W2a) [16 x 32] per node; A rows = k = l15 ----
  f32x4 p00 = {0.f,0.f,0.f,0.f}, p01 = {0.f,0.f,0.f,0.f};   // node0, h-tile 0/1
  f32x4 p10 = {0.f,0.f,0.f,0.f}, p11 = {0.f,0.f,0.f,0.f};   // node1
#pragma unroll
  for (int s = 0; s < 4; ++s) {
    half8_t B0 = *(const half8_t*)(w2a + ((size_t)(0 * 6 + s) * 64 + lane) * 8);
    half8_t B1 = *(const half8_t*)(w2a + ((size_t)(1 * 6 + s) * 64 + lane) * 8);
    float4 a0 = *(const float4*)(nrow0 + 32 * s + 8 * q);
    float4 a1 = *(const float4*)(nrow0 + 32 * s + 8 * q + 4);
    float4 b0 = *(const float4*)(nrow1 + 32 * s + 8 * q);
    float4 b1 = *(const float4*)(nrow1 + 32 * s + 8 * q + 4);
    half8_t A0 = cvt8(a0, a1);
    half8_t A1 = cvt8(b0, b1);
    p00 = __builtin_amdgcn_mfma_f32_16x16x32_f16(A0, B0, p00, 0, 0, 0);
    p01 = __builtin_amdgcn_mfma_f32_16x16x32_f16(A0, B1, p01, 0, 0, 0);
    p10 = __builtin_amdgcn_mfma_f32_16x16x32_f16(A1, B0, p10, 0, 0, 0);
    p11 = __builtin_amdgcn_mfma_f32_16x16x32_f16(A1, B1, p11, 0, 0, 0);
  }
#pragma unroll
  for (int s = 0; s < 2; ++s) {
    half8_t B0 = *(const half8_t*)(w2a + ((size_t)(0 * 6 + 4 + s) * 64 + lane) * 8);
    half8_t B1 = *(const half8_t*)(w2a + ((size_t)(1 * 6 + 4 + s) * 64 + lane) * 8);
    float4 a0 = *(const float4*)(erow0 + 32 * s + 8 * q);
    float4 a1 = *(const float4*)(erow0 + 32 * s + 8 * q + 4);
    float4 b0 = *(const float4*)(erow1 + 32 * s + 8 * q);
    float4 b1 = *(const float4*)(erow1 + 32 * s + 8 * q + 4);
    half8_t A0 = cvt8(a0, a1);
    half8_t A1 = cvt8(b0, b1);
    p00 = __builtin_amdgcn_mfma_f32_16x16x32_f16(A0, B0, p00, 0, 0, 0);
    p01 = __builtin_amdgcn_mfma_f32_16x16x32_f16(A0, B1, p01, 0, 0, 0);
    p10 = __builtin_amdgcn_mfma_f32_16x16x32_f16(A1, B0, p10, 0, 0, 0);
    p11 = __builtin_amdgcn_mfma_f32_16x16x32_f16(A1, B1, p11, 0, 0, 0);
  }

  // u from pre_kernel (parked at out[n][128:160]); broadcast loads
  const float u00 = out[(size_t)n0 * 256 + 128 + l15];
  const float u01 = out[(size_t)n0 * 256 + 144 + l15];
  const float u10 = out[(size_t)(n0 + 1) * 256 + 128 + l15];
  const float u11 = out[(size_t)(n0 + 1) * 256 + 144 + l15];

  // s[k] = sum_h tanh(S[k][h]) * u[h]; lane holds col h=l15(+16), rows k=4q+r
  float sv0[4], sv1[4];
#pragma unroll
  for (int r = 0; r < 4; ++r) {
    sv0[r] = tanhf(p00[r]) * u00 + tanhf(p01[r]) * u01;
    sv1[r] = tanhf(p10[r]) * u10 + tanhf(p11[r]) * u11;
  }
#pragma unroll
  for (int off = 1; off <= 8; off <<= 1)
#pragma unroll
    for (int r = 0; r < 4; ++r) {
      sv0[r] += __shfl_xor(sv0[r], off);   // reduce over 16 cols (h)
      sv1[r] += __shfl_xor(sv1[r], off);
    }

  // ---- masked softmax fully in registers (all 64 lanes participate) ----
  float e0[4], e1[4];
  float mx0 = -3.4e38f, mx1 = -3.4e38f;
#pragma unroll
  for (int r = 0; r < 4; ++r) {
    sv0[r] -= 9999999.0f * mask[(size_t)n0 * GK + 4 * q + r];
    sv1[r] -= 9999999.0f * mask[(size_t)(n0 + 1) * GK + 4 * q + r];
    mx0 = fmaxf(mx0, sv0[r]);
    mx1 = fmaxf(mx1, sv1[r]);
  }
  mx0 = fmaxf(mx0, __shfl_xor(mx0, 16)); mx0 = fmaxf(mx0, __shfl_xor(mx0, 32));
  mx1 = fmaxf(mx1, __shfl_xor(mx1, 16)); mx1 = fmaxf(mx1, __shfl_xor(mx1, 32));
  float sm0 = 0.f, sm1 = 0.f;
#pragma unroll
  for (int r = 0; r < 4; ++r) {
    e0[r] = expf(sv0[r] - mx0); sm0 += e0[r];
    e1[r] = expf(sv1[r] - mx1); sm1 += e1[r];
  }
  sm0 += __shfl_xor(sm0, 16); sm0 += __shfl_xor(sm0, 32);
  sm1 += __shfl_xor(sm1, 16); sm1 += __shfl_xor(sm1, 32);
  const float rs0 = 1.0f / sm0, rs1 = 1.0f / sm1;
#pragma unroll
  for (int r = 0; r < 4; ++r) { e0[r] *= rs0; e1[r] *= rs1; }  // weight, k=4q+r

  // ---- aggregation: lane owns d = lane, 64+lane, edge lane; ne from L2 ----
  float a00 = 0.f, a01 = 0.f, a02 = 0.f;
  float a10 = 0.f, a11 = 0.f, a12 = 0.f;
#pragma unroll
  for (int k = 0; k < GK; ++k) {
    float w0 = __shfl(e0[k & 3], (k & 12) << 2);  // lane 16*(k>>2) holds k's wt
    float w1 = __shfl(e1[k & 3], (k & 12) << 2);
    a00 = fmaf(w0, nbase0[k * DIN + lane], a00);
    a01 = fmaf(w0, nbase0[k * DIN + 64 + lane], a01);
    a02 = fmaf(w0, ebase0[k * DED + lane], a02);
    a10 = fmaf(w1, nbase1[k * DIN + lane], a10);
    a11 = fmaf(w1, nbase1[k * DIN + 64 + lane], a11);
    a12 = fmaf(w1, ebase1[k * DED + lane], a12);
  }
  aggL[wave * 2 + 0][lane] = (half_t)a00;
  aggL[wave * 2 + 0][64 + lane] = (half_t)a01;
  aggL[wave * 2 + 0][128 + lane] = (half_t)a02;
  aggL[wave * 2 + 1][lane] = (half_t)a10;
  aggL[wave * 2 + 1][64 + lane] = (half_t)a11;
  aggL[wave * 2 + 1][128 + lane] = (half_t)a12;
  __syncthreads();

  // ---- epilogue: out[:,128:] = elu(agg @ Wfn); wave = col tile, 16 rows ----
  f32x4 accn = {0.f, 0.f, 0.f, 0.f};
#pragma unroll
  for (int s = 0; s < 6; ++s) {
    half8_t A = *(const half8_t*)(&aggL[l15][32 * s + 8 * q]);
    half8_t B = *(const half8_t*)(wfn + ((size_t)(wave * 6 + s) * 64 + lane) * 8);
    accn = __builtin_amdgcn_mfma_f32_16x16x32_f16(A, B, accn, 0, 0, 0);
  }
  const size_t ob = (size_t)nb * 256;
#pragma unroll
  for (int r = 0; r < 4; ++r) {
    int m = 4 * q + r;                   // C row = node 0..15, all valid
    out[ob + (size_t)m * 256 + 128 + wave * 16 + l15] = elu(accn[r]);
  }
}

extern "C" void kernel_launch(void* const* d_in, const int* in_sizes, int n_in,
                              void* d_out, int out_size, void* d_ws, size_t ws_size,
                              hipStream_t stream) {
  const float* x     = (const float*)d_in[0];
  const float* neibs = (const float*)d_in[1];
  const float* edge  = (const float*)d_in[2];
  const float* mask  = (const float*)d_in[3];
  const float* W1a   = (const float*)d_in[4];
  const float* W1b   = (const float*)d_in[5];
  const float* W2a   = (const float*)d_in[6];
  const float* W2b   = (const float*)d_in[7];
  const float* Wfx   = (const float*)d_in[8];
  const float* Wfn   = (const float*)d_in[9];
  float* out = (float*)d_out;
  unsigned char* ws = (unsigned char*)d_ws;

  hipLaunchKernelGGL(setup_kernel, dim3(64), dim3(256), 0, stream,
                     W1a, W1b, W2a, W2b, Wfx, Wfn, ws);
  hipLaunchKernelGGL(pre_kernel, dim3((NN + 63) / 64), dim3(256), 0, stream,
                     x, ws, out);
  hipLaunchKernelGGL(attn_kernel, dim3(NN / 16), dim3(512), 0, stream,
                     neibs, edge, mask, ws, out);
}